// Round 6
// baseline (26.375 us; speedup 1.0000x reference)
//
#include <hip/hip_runtime.h>

// CustomEmbedding: out[t, :] = sin-row if x[t] < 1000 else weight[x[t], :]
// Page-locality probe: ONE wave owns a full 2KB row (2 x dwordx4 per lane,
// both halves issued back-to-back -> maximal same-DRAM-page bursts), with
// 2 rows (tokens) in flight per wave for MLP. nt stores for the output.

#define DIM 512
#define NUM_NUM 1000
#define GRID_BLOCKS 2048    // x4 waves = 8192 waves; 2 tokens/iter each

typedef float floatx4 __attribute__((ext_vector_type(4)));

__global__ __launch_bounds__(256) void CustomEmbedding_kernel(
    const int* __restrict__ x,
    const float* __restrict__ weight,
    float* __restrict__ out,
    int n_tok)
{
    int lane    = threadIdx.x & 63;
    int wave_g  = (blockIdx.x * 256 + threadIdx.x) >> 6;   // global wave id
    int n_waves = (gridDim.x * 256) >> 6;                   // 8192

    int dA = lane << 2;          // floats [dA, dA+3]   (first 1KB half)
    int dB = 256 + dA;           // floats [dB, dB+3]   (second 1KB half)

    // each wave processes tokens wave_g, wave_g + n_waves, ... two at a time
    for (int t0 = wave_g; t0 < n_tok; t0 += 2 * n_waves) {
        int t1 = t0 + n_waves;
        bool has1 = (t1 < n_tok);

        // independent index loads
        int idx0 = x[t0];
        int idx1 = has1 ? x[t1] : 0;

        // four row loads in flight (2KB per token, same-page back-to-back)
        const floatx4* r0 = reinterpret_cast<const floatx4*>(weight + (size_t)idx0 * DIM);
        const floatx4* r1 = reinterpret_cast<const floatx4*>(weight + (size_t)idx1 * DIM);
        floatx4 a0 = r0[lane];          // dA half, token 0
        floatx4 b0 = r0[64 + lane];     // dB half, token 0
        floatx4 a1 = r1[lane];
        floatx4 b1 = r1[64 + lane];

        // numeric override (wave-uniform branches)
        if (idx0 < NUM_NUM) {
            float base = (float)idx0 * 1e-3f;
            a0.x = sinf(base * (float)(dA + 1)); a0.y = sinf(base * (float)(dA + 2));
            a0.z = sinf(base * (float)(dA + 3)); a0.w = sinf(base * (float)(dA + 4));
            b0.x = sinf(base * (float)(dB + 1)); b0.y = sinf(base * (float)(dB + 2));
            b0.z = sinf(base * (float)(dB + 3)); b0.w = sinf(base * (float)(dB + 4));
        }
        if (has1 && idx1 < NUM_NUM) {
            float base = (float)idx1 * 1e-3f;
            a1.x = sinf(base * (float)(dA + 1)); a1.y = sinf(base * (float)(dA + 2));
            a1.z = sinf(base * (float)(dA + 3)); a1.w = sinf(base * (float)(dA + 4));
            b1.x = sinf(base * (float)(dB + 1)); b1.y = sinf(base * (float)(dB + 2));
            b1.z = sinf(base * (float)(dB + 3)); b1.w = sinf(base * (float)(dB + 4));
        }

        // nt streaming stores, full row per wave
        floatx4* o0 = reinterpret_cast<floatx4*>(out + (size_t)t0 * DIM);
        __builtin_nontemporal_store(a0, o0 + lane);
        __builtin_nontemporal_store(b0, o0 + 64 + lane);
        if (has1) {
            floatx4* o1 = reinterpret_cast<floatx4*>(out + (size_t)t1 * DIM);
            __builtin_nontemporal_store(a1, o1 + lane);
            __builtin_nontemporal_store(b1, o1 + 64 + lane);
        }
    }
}

extern "C" void kernel_launch(void* const* d_in, const int* in_sizes, int n_in,
                              void* d_out, int out_size, void* d_ws, size_t ws_size,
                              hipStream_t stream) {
    const int*   x      = (const int*)d_in[0];
    const float* weight = (const float*)d_in[1];
    // d_in[2] (num_value) and d_in[3] (is_num) are pure functions of the id; unused.
    float* out = (float*)d_out;

    int n_tok = in_sizes[0];    // 8 * 4096 = 32768
    CustomEmbedding_kernel<<<GRID_BLOCKS, 256, 0, stream>>>(x, weight, out, n_tok);
}